// Round 5
// baseline (135.172 us; speedup 1.0000x reference)
//
#include <hip/hip_runtime.h>
#include <math.h>

#define BB 128
#define PP 1024
#define LL 128
#define NROWS (BB * PP)      // 131072
#define EPS_VAR 1e-5f
#define NBLK 1024            // one block per 128-row chunk
#define ROWS_PER_BLK 128
#define CHUNKS 8             // chunks per b

typedef float vfloat4 __attribute__((ext_vector_type(4)));

__device__ __forceinline__ bool is_nan_bits(float f) {
    return (__float_as_uint(f) & 0x7fffffffu) > 0x7f800000u;
}

// ---------------------------------------------------------------------------
// Kernel 1: per-chunk NaN-aware totals (sum, sum^2, nan count) over 128 rows.
// Block g covers global rows [g*128, (g+1)*128) == one contiguous 64 KB slab.
// Pure streaming read; populates L3 for kernel 2.
// ---------------------------------------------------------------------------
__global__ __launch_bounds__(256) void k_chunktot(const float* __restrict__ x,
                                                  float4* __restrict__ tot) {
    __shared__ float ws1[4], ws2[4], wsc[4];
    const int g = blockIdx.x;
    const int t = threadIdx.x;
    const int lane = t & 63;
    const int wav  = t >> 6;

    const vfloat4* px = (const vfloat4*)(x + (size_t)g * (ROWS_PER_BLK * LL));

    float s1 = 0.f, s2 = 0.f, c = 0.f;
#pragma unroll
    for (int i = 0; i < 16; ++i) {
        const vfloat4 v = px[t + 256 * i];
#pragma unroll
        for (int j = 0; j < 4; ++j) {
            const float f = v[j];
            const bool nn = is_nan_bits(f);
            const float u = nn ? 0.f : f;
            s1 += u; s2 += u * u; c += nn ? 1.f : 0.f;
        }
    }
#pragma unroll
    for (int off = 32; off >= 1; off >>= 1) {
        s1 += __shfl_xor(s1, off);
        s2 += __shfl_xor(s2, off);
        c  += __shfl_xor(c,  off);
    }
    if (lane == 0) { ws1[wav] = s1; ws2[wav] = s2; wsc[wav] = c; }
    __syncthreads();
    if (t == 0) {
        tot[g] = make_float4(ws1[0] + ws1[1] + ws1[2] + ws1[3],
                             ws2[0] + ws2[1] + ws2[2] + ws2[3],
                             wsc[0] + wsc[1] + wsc[2] + wsc[3], 0.f);
    }
}

// NaN forward-fill fallback for one row (never taken on NaN-free bench input).
__device__ __attribute__((noinline)) void slow_row(const float* __restrict__ x,
                                                   float* __restrict__ out,
                                                   size_t base, int sl,
                                                   float mean, float istd,
                                                   float4 vv) {
    const float vf[4] = {vv.x, vv.y, vv.z, vv.w};
    for (int j = 0; j < 4; ++j) {
        const int l = sl * 4 + j;
        if (!is_nan_bits(vf[j])) {
            out[base + l] = (vf[j] - mean) * istd;
        } else {
            float res = 0.0f;  // x_temp[0]==0 when no prior valid exists
            for (int k = l - 1; k >= 0; --k) {
                const float xv = x[base + k];
                if (!is_nan_bits(xv)) { res = (xv - mean) * istd; break; }
            }
            out[base + l] = res;
        }
    }
}

// ---------------------------------------------------------------------------
// Kernel 2: per-row stats (x from L3) -> block-local scan over 128 rows ->
// add exclusive prefix of preceding chunk totals -> normalize -> NT store.
// ---------------------------------------------------------------------------
__global__ __launch_bounds__(256, 4) void k_scan_norm(const float* __restrict__ x,
                                                      const float4* __restrict__ tot,
                                                      float* __restrict__ out) {
    __shared__ float ls1[ROWS_PER_BLK], ls2[ROWS_PER_BLK], lsc[ROWS_PER_BLK];
    __shared__ float wtot[3];
    __shared__ float off_s[3];

    const int g     = blockIdx.x;
    const int b     = g >> 3;
    const int chunk = g & 7;
    const int t     = threadIdx.x;
    const int sl    = t & 31;            // lane within half-wave
    const int h     = t >> 5;            // half-wave id 0..7
    const int p0    = chunk * ROWS_PER_BLK;
    const size_t rowbase = (size_t)b * PP + p0;

    // ---- phase 1: load x (register-resident), per-row NaN-aware stats ----
    float4 v[16];
#pragma unroll
    for (int i = 0; i < 16; ++i) {
        const int r = h + 8 * i;
        v[i] = ((const float4*)(x + (rowbase + r) * LL))[sl];
    }
#pragma unroll
    for (int i = 0; i < 16; ++i) {
        const int r = h + 8 * i;
        const float f[4] = {v[i].x, v[i].y, v[i].z, v[i].w};
        float s1 = 0.f, s2 = 0.f, c = 0.f;
#pragma unroll
        for (int j = 0; j < 4; ++j) {
            const bool nn = is_nan_bits(f[j]);
            const float u = nn ? 0.f : f[j];
            s1 += u; s2 += u * u; c += nn ? 1.f : 0.f;
        }
#pragma unroll
        for (int off = 16; off >= 1; off >>= 1) {
            s1 += __shfl_xor(s1, off);
            s2 += __shfl_xor(s2, off);
            c  += __shfl_xor(c,  off);
        }
        if (sl == 0) { ls1[r] = s1; ls2[r] = s2; lsc[r] = c; }
    }
    __syncthreads();

    // ---- phase 2: inclusive scan over the 128 rows (threads 0..127) ----
    const int lane = t & 63;
    float a1 = 0.f, a2 = 0.f, ac = 0.f;
    if (t < 128) { a1 = ls1[t]; a2 = ls2[t]; ac = lsc[t]; }
#pragma unroll
    for (int off = 1; off < 64; off <<= 1) {
        const float u1 = __shfl_up(a1, off);
        const float u2 = __shfl_up(a2, off);
        const float u3 = __shfl_up(ac, off);
        if (lane >= off) { a1 += u1; a2 += u2; ac += u3; }
    }
    if (t == 63) { wtot[0] = a1; wtot[1] = a2; wtot[2] = ac; }
    __syncthreads();
    if (t >= 64 && t < 128) { a1 += wtot[0]; a2 += wtot[1]; ac += wtot[2]; }
    if (t < 128) { ls1[t] = a1; ls2[t] = a2; lsc[t] = ac; }

    // exclusive prefix of preceding chunk totals for this b (written by k1)
    if (t == 0) {
        float o1 = 0.f, o2 = 0.f, oc = 0.f;
        for (int j = 0; j < chunk; ++j) {
            const float4 ct = tot[(b << 3) + j];
            o1 += ct.x; o2 += ct.y; oc += ct.z;
        }
        off_s[0] = o1; off_s[1] = o2; off_s[2] = oc;
    }
    __syncthreads();
    const float o1 = off_s[0], o2 = off_s[1], oc = off_s[2];

    // ---- phase 3: normalize from registers, nontemporal store ----
#pragma unroll
    for (int i = 0; i < 16; ++i) {
        const int r = h + 8 * i;
        const float cum1 = o1 + ls1[r];
        const float cum2 = o2 + ls2[r];
        const float cumc = oc + lsc[r];
        const int p = p0 + r;
        const float cnt  = (float)((p + 1) * LL) - cumc;
        const float mean = cum1 / cnt;
        const float var  = cum2 / cnt - mean * mean;
        const float istd = 1.0f / sqrtf(var + EPS_VAR);
        const float4 vv = v[i];
        const size_t base = (rowbase + r) * (size_t)LL;

        const bool anynan = is_nan_bits(vv.x) | is_nan_bits(vv.y) |
                            is_nan_bits(vv.z) | is_nan_bits(vv.w);
        if (__ballot(anynan) == 0ull) {
            vfloat4 y = {(vv.x - mean) * istd, (vv.y - mean) * istd,
                         (vv.z - mean) * istd, (vv.w - mean) * istd};
            __builtin_nontemporal_store(y, &((vfloat4*)(out + base))[sl]);
        } else {
            slow_row(x, out, base, sl, mean, istd, vv);
        }
    }
}

extern "C" void kernel_launch(void* const* d_in, const int* in_sizes, int n_in,
                              void* d_out, int out_size, void* d_ws, size_t ws_size,
                              hipStream_t stream) {
    const float* x = (const float*)d_in[0];
    float* outp = (float*)d_out;
    float4* tot = (float4*)d_ws;  // 1024 * 16 B = 16 KiB

    k_chunktot<<<NBLK, 256, 0, stream>>>(x, tot);
    k_scan_norm<<<NBLK, 256, 0, stream>>>(x, tot, outp);
}

// Round 6
// 129.828 us; speedup vs baseline: 1.0412x; 1.0412x over previous
//
#include <hip/hip_runtime.h>
#include <math.h>

#define BB 128
#define PP 1024
#define LL 128
#define NROWS (BB * PP)      // 131072
#define EPS_VAR 1e-5f
#define NBLK 1024            // one block per 128-row chunk
#define ROWS_PER_BLK 128
#define CHUNKS 8             // chunks per b

typedef float vfloat4 __attribute__((ext_vector_type(4)));

__device__ __forceinline__ bool is_nan_bits(float f) {
    return (__float_as_uint(f) & 0x7fffffffu) > 0x7f800000u;
}

// ---------------------------------------------------------------------------
// Kernel 1: one block per 128-row chunk (64 KB slab). Streams the slab once:
// per-row NaN-aware stats (half-wave butterfly) -> rowstats[], plus a
// deterministic block reduction -> chunkTot[g]. No data held across barriers.
// ---------------------------------------------------------------------------
__global__ __launch_bounds__(256) void k_chunkstats(const float* __restrict__ x,
                                                    float4* __restrict__ rowstats,
                                                    float4* __restrict__ chunkTot) {
    __shared__ float4 lrow[ROWS_PER_BLK];
    __shared__ float ws1[4], ws2[4], wsc[4];

    const int g    = blockIdx.x;
    const int t    = threadIdx.x;
    const int sl   = t & 31;   // lane within half-wave
    const int h    = t >> 5;   // half-wave id 0..7
    const int lane = t & 63;
    const int wav  = t >> 6;

    const float* slab = x + (size_t)g * (ROWS_PER_BLK * LL);

    float c1 = 0.f, c2 = 0.f, cc = 0.f;   // thread-local chunk accumulators
#pragma unroll
    for (int i = 0; i < 16; ++i) {
        const int r = h + 8 * i;
        const float4 v = ((const float4*)(slab + (size_t)r * LL))[sl];
        const float f[4] = {v.x, v.y, v.z, v.w};
        float s1 = 0.f, s2 = 0.f, c = 0.f;
#pragma unroll
        for (int j = 0; j < 4; ++j) {
            const bool nn = is_nan_bits(f[j]);
            const float u = nn ? 0.f : f[j];
            s1 += u; s2 += u * u; c += nn ? 1.f : 0.f;
        }
        c1 += s1; c2 += s2; cc += c;      // pre-butterfly partials
#pragma unroll
        for (int off = 16; off >= 1; off >>= 1) {
            s1 += __shfl_xor(s1, off);
            s2 += __shfl_xor(s2, off);
            c  += __shfl_xor(c,  off);
        }
        if (sl == 0) lrow[r] = make_float4(s1, s2, c, 0.f);
    }

    // block-reduce the chunk totals (wave butterfly -> LDS -> thread 0)
#pragma unroll
    for (int off = 32; off >= 1; off >>= 1) {
        c1 += __shfl_xor(c1, off);
        c2 += __shfl_xor(c2, off);
        cc += __shfl_xor(cc, off);
    }
    if (lane == 0) { ws1[wav] = c1; ws2[wav] = c2; wsc[wav] = cc; }
    __syncthreads();

    if (t < ROWS_PER_BLK)
        rowstats[(size_t)g * ROWS_PER_BLK + t] = lrow[t];
    if (t == 0)
        chunkTot[g] = make_float4(ws1[0] + ws1[1] + ws1[2] + ws1[3],
                                  ws2[0] + ws2[1] + ws2[2] + ws2[3],
                                  wsc[0] + wsc[1] + wsc[2] + wsc[3], 0.f);
}

// NaN forward-fill fallback for one row (never taken on NaN-free bench input).
__device__ __attribute__((noinline)) void slow_row(const float* __restrict__ x,
                                                   float* __restrict__ out,
                                                   size_t base, int sl,
                                                   float mean, float istd,
                                                   float4 vv) {
    const float vf[4] = {vv.x, vv.y, vv.z, vv.w};
    for (int j = 0; j < 4; ++j) {
        const int l = sl * 4 + j;
        if (!is_nan_bits(vf[j])) {
            out[base + l] = (vf[j] - mean) * istd;
        } else {
            float res = 0.0f;  // x_temp[0]==0 when no prior valid exists
            for (int k = l - 1; k >= 0; --k) {
                const float xv = x[base + k];
                if (!is_nan_bits(xv)) { res = (xv - mean) * istd; break; }
            }
            out[base + l] = res;
        }
    }
}

// ---------------------------------------------------------------------------
// Kernel 2: scan the 128 row-stats (L2-hot), add exclusive prefix of
// preceding chunk totals, then normalize re-loading x from L3 immediately
// before use (no live array across barriers -> no spill). NT stores.
// ---------------------------------------------------------------------------
__global__ __launch_bounds__(256) void k_scan_norm(const float* __restrict__ x,
                                                   const float4* __restrict__ rowstats,
                                                   const float4* __restrict__ chunkTot,
                                                   float* __restrict__ out) {
    __shared__ float ls1[ROWS_PER_BLK], ls2[ROWS_PER_BLK], lsc[ROWS_PER_BLK];
    __shared__ float wtot[3];
    __shared__ float4 pre[CHUNKS];

    const int g     = blockIdx.x;
    const int b     = g >> 3;
    const int chunk = g & 7;
    const int t     = threadIdx.x;
    const int sl    = t & 31;
    const int h     = t >> 5;
    const int lane  = t & 63;
    const int p0    = chunk * ROWS_PER_BLK;
    const size_t rowbase = (size_t)b * PP + p0;

    // load row stats + wave-level inclusive scan (threads 0..127, 2 waves)
    float a1 = 0.f, a2 = 0.f, ac = 0.f;
    if (t < ROWS_PER_BLK) {
        const float4 rs = rowstats[(size_t)g * ROWS_PER_BLK + t];
        a1 = rs.x; a2 = rs.y; ac = rs.z;
    }
#pragma unroll
    for (int off = 1; off < 64; off <<= 1) {
        const float u1 = __shfl_up(a1, off);
        const float u2 = __shfl_up(a2, off);
        const float u3 = __shfl_up(ac, off);
        if (lane >= off) { a1 += u1; a2 += u2; ac += u3; }
    }
    if (t == 63) { wtot[0] = a1; wtot[1] = a2; wtot[2] = ac; }
    if (t < chunk) pre[t] = chunkTot[(b << 3) + t];   // preceding chunk totals
    __syncthreads();
    if (t >= 64 && t < 128) { a1 += wtot[0]; a2 += wtot[1]; ac += wtot[2]; }
    if (t < ROWS_PER_BLK) { ls1[t] = a1; ls2[t] = a2; lsc[t] = ac; }
    __syncthreads();

    // exclusive cross-chunk prefix (broadcast LDS reads, per-thread)
    float o1 = 0.f, o2 = 0.f, oc = 0.f;
#pragma unroll
    for (int j = 0; j < CHUNKS - 1; ++j) {
        if (j < chunk) { o1 += pre[j].x; o2 += pre[j].y; oc += pre[j].z; }
    }

    // normalize: load x fresh (L3-hot), FMA, nontemporal store
#pragma unroll
    for (int i = 0; i < 16; ++i) {
        const int r = h + 8 * i;
        const size_t base = (rowbase + r) * (size_t)LL;
        const float4 vv = ((const float4*)(x + base))[sl];

        const float cum1 = o1 + ls1[r];
        const float cum2 = o2 + ls2[r];
        const float cumc = oc + lsc[r];
        const int p = p0 + r;
        const float cnt  = (float)((p + 1) * LL) - cumc;
        const float mean = cum1 / cnt;
        const float var  = cum2 / cnt - mean * mean;
        const float istd = 1.0f / sqrtf(var + EPS_VAR);

        const bool anynan = is_nan_bits(vv.x) | is_nan_bits(vv.y) |
                            is_nan_bits(vv.z) | is_nan_bits(vv.w);
        if (__ballot(anynan) == 0ull) {
            vfloat4 y = {(vv.x - mean) * istd, (vv.y - mean) * istd,
                         (vv.z - mean) * istd, (vv.w - mean) * istd};
            __builtin_nontemporal_store(y, &((vfloat4*)(out + base))[sl]);
        } else {
            slow_row(x, out, base, sl, mean, istd, vv);
        }
    }
}

extern "C" void kernel_launch(void* const* d_in, const int* in_sizes, int n_in,
                              void* d_out, int out_size, void* d_ws, size_t ws_size,
                              hipStream_t stream) {
    const float* x = (const float*)d_in[0];
    float* outp = (float*)d_out;

    float4* rowstats = (float4*)d_ws;                       // 131072 * 16 B = 2 MiB
    float4* chunkTot = (float4*)((char*)d_ws + (size_t)NROWS * sizeof(float4)); // 16 KiB

    k_chunkstats<<<NBLK, 256, 0, stream>>>(x, rowstats, chunkTot);
    k_scan_norm<<<NBLK, 256, 0, stream>>>(x, rowstats, chunkTot, outp);
}